// Round 4
// baseline (445.253 us; speedup 1.0000x reference)
//
#include <hip/hip_runtime.h>

typedef unsigned short u16;
typedef unsigned int   u32;
typedef __attribute__((ext_vector_type(4))) float  f32x4;
typedef __attribute__((ext_vector_type(8))) __bf16 bf16x8;
typedef __attribute__((ext_vector_type(4))) u32    u32x4;
typedef __attribute__((ext_vector_type(2))) u32    u32x2;

#define B_ 4
#define S_ 2048
#define E_ 512
#define H_ 8
#define D_ 64
// tokens M = B*S = 8192

__device__ __forceinline__ u16 f2bf(float f) {
  union { float f; u32 u; } a; a.f = f;
  u32 r = a.u + 0x7FFFu + ((a.u >> 16) & 1u);   // RNE
  return (u16)(r >> 16);
}
__device__ __forceinline__ float bf2f(u16 u) {
  union { u32 u; float f; } a; a.u = (u32)u << 16;
  return a.f;
}

// ---------------- weight fp32 -> bf16 convert ----------------
__global__ __launch_bounds__(256) void cvt_k(const float* __restrict__ s,
                                             u16* __restrict__ d, int n) {
  int i = (blockIdx.x * 256 + threadIdx.x) * 4;
  if (i >= n) return;
  f32x4 v = *(const f32x4*)(s + i);
  u32x2 o;
  o.x = (u32)f2bf(v[0]) | ((u32)f2bf(v[1]) << 16);
  o.y = (u32)f2bf(v[2]) | ((u32)f2bf(v[3]) << 16);
  *(u32x2*)(d + i) = o;
}

// ---------------- RoPE cos/sin table ----------------
__global__ __launch_bounds__(256) void ropetab_k(float* __restrict__ ct,
                                                 float* __restrict__ st) {
  int idx = blockIdx.x * 256 + threadIdx.x;   // S_*64 total
  int s = idx >> 6, j = idx & 63;
  float f = powf(10000.f, -(float)(j & 31) * (1.f / 32.f));
  float ang = (float)s * f;
  ct[idx] = cosf(ang);
  st[idx] = sinf(ang);
}

// ---------------- RMSNorm (row of 512), fp32 in -> bf16 out ----------------
__global__ __launch_bounds__(256) void rmsnorm_k(const float* __restrict__ x,
                                                 const float* __restrict__ wv,
                                                 u16* __restrict__ o) {
  const int row = blockIdx.x;
  const int t = threadIdx.x;
  const float* xr = x + (size_t)row * E_;
  float v0 = xr[t], v1 = xr[t + 256];
  float ss = v0 * v0 + v1 * v1;
#pragma unroll
  for (int m = 1; m < 64; m <<= 1) ss += __shfl_xor(ss, m, 64);
  __shared__ float red[4];
  if ((t & 63) == 0) red[t >> 6] = ss;
  __syncthreads();
  float tot = red[0] + red[1] + red[2] + red[3];
  float rms = 1.f / sqrtf(tot * (1.f / (float)E_) + 1e-6f);
  o[(size_t)row * E_ + t]       = f2bf(v0 * rms * wv[t]);
  o[(size_t)row * E_ + t + 256] = f2bf(v1 * rms * wv[t + 256]);
}

// ------------- column sums (xm) + batch sum/sumsq of h -------------
// stats layout (floats): [0..3]=sum_b, [4..7]=sumsq_b, [8..2055]=xm_sum(b*512+e), int ws at [2056]
__global__ __launch_bounds__(256) void colsum_k(const u16* __restrict__ h,
                                                float* __restrict__ st) {
  const int b = blockIdx.x >> 3, ck = blockIdx.x & 7;  // 8 chunks of 256 rows
  const u16* hb = h + ((size_t)b * S_ + ck * 256) * E_;
  const int t = threadIdx.x;
  float a0 = 0, a1 = 0, s = 0, sq = 0;
  for (int r = 0; r < 256; ++r) {
    float v0 = bf2f(hb[(size_t)r * E_ + t]);
    float v1 = bf2f(hb[(size_t)r * E_ + t + 256]);
    a0 += v0; a1 += v1;
    s += v0 + v1; sq += v0 * v0 + v1 * v1;
  }
  atomicAdd(&st[8 + b * E_ + t], a0);
  atomicAdd(&st[8 + b * E_ + t + 256], a1);
#pragma unroll
  for (int m = 1; m < 64; m <<= 1) { s += __shfl_xor(s, m, 64); sq += __shfl_xor(sq, m, 64); }
  if ((t & 63) == 0) { atomicAdd(&st[b], s); atomicAdd(&st[4 + b], sq); }
}

// ------------- complexity -> window size scalar -------------
__global__ __launch_bounds__(128) void wscalc_k(float* __restrict__ st,
                                                const float* __restrict__ w1,
                                                const float* __restrict__ w2) {
  const int j = threadIdx.x;  // 0..127
  __shared__ float comp[4];
  __shared__ float tw[2];
  // dot[b] = xm_sum[b] . w1[j]  (load each w1 element once, reuse for 4 batches)
  float dot[4] = {0.f, 0.f, 0.f, 0.f};
  const float* w1r = w1 + (size_t)j * E_;
  for (int e = 0; e < E_; ++e) {
    float wv = w1r[e];
    dot[0] += st[8 + 0 * E_ + e] * wv;
    dot[1] += st[8 + 1 * E_ + e] * wv;
    dot[2] += st[8 + 2 * E_ + e] * wv;
    dot[3] += st[8 + 3 * E_ + e] * wv;
  }
  for (int b = 0; b < 4; ++b) {
    float d = dot[b] * (1.f / (float)S_);           // xm = colsum / S
    float si = d / (1.f + __expf(-d));              // silu
    float term = si * w2[j];
#pragma unroll
    for (int m = 1; m < 64; m <<= 1) term += __shfl_xor(term, m, 64);
    __syncthreads();
    if ((j & 63) == 0) tw[j >> 6] = term;
    __syncthreads();
    if (j == 0) {
      float pre = tw[0] + tw[1];
      float learned = 1.f / (1.f + __expf(-pre));
      const float n = (float)S_ * (float)E_;
      float sum = st[b], ssq = st[4 + b];
      float var = (ssq - sum * sum / n) / (n - 1.f);
      float vn = 1.f / (1.f + __expf(-(var * 10.f - 5.f)));
      comp[b] = 0.5f * (vn + learned);
    }
    __syncthreads();
  }
  if (j == 0) {
    float mean = 0.25f * (comp[0] + comp[1] + comp[2] + comp[3]);
    float wsf = 256.f + mean * 768.f;
    int v = (int)wsf;                               // trunc like astype(int32)
    v = v < 256 ? 256 : (v > S_ ? S_ : v);
    ((int*)st)[2056] = v;
  }
}

// ---------------- generic 128x128 bf16 MFMA GEMM: C = A[M][K] * W[N][K]^T ----------------
// EPI: 0 = QKV (RoPE + scatter to Q/K/Vt), 1 = +resid -> f32 out, 2 = store bf16, 3 = silu(gate)*acc -> bf16
struct EpiArgs {
  u16* q; u16* k; u16* vt;
  const float* cosT; const float* sinT;
  const float* resid; float* outf;
  const u16* gate; u16* outb;
};

template <int N, int K, int EPI>
__global__ __launch_bounds__(256) void gemm_k(const u16* __restrict__ A,
                                              const u16* __restrict__ W,
                                              EpiArgs ea) {
  __shared__ u16 sA[128 * 32];
  __shared__ u16 sB[128 * 32];
  const int tid = threadIdx.x;
  const int bm = blockIdx.x, bn = blockIdx.y;
  const int lane = tid & 63, w = tid >> 6;
  const int g = lane >> 4, c = lane & 15;
  const int wr = w >> 1, wc = w & 1;

  // staging: thread -> (row, 16B chunk); XOR swizzle on chunk by (row>>1)&3
  const int srow = tid >> 2, sch = tid & 3;
  const u16* gA0 = A + (size_t)(bm * 128 + srow) * K + sch * 8;
  const u16* gB0 = W + (size_t)(bn * 128 + srow) * K + sch * 8;
  const int so0 = srow * 32 + ((sch * 8) ^ (((srow >> 1) & 3) * 8));
  const int so1 = so0 + 64 * 32;

  u32x4 ra0 = *(const u32x4*)gA0;
  u32x4 ra1 = *(const u32x4*)(gA0 + (size_t)64 * K);
  u32x4 rb0 = *(const u32x4*)gB0;
  u32x4 rb1 = *(const u32x4*)(gB0 + (size_t)64 * K);

  f32x4 acc[4][4];
  f32x4 zz = {0.f, 0.f, 0.f, 0.f};
#pragma unroll
  for (int i = 0; i < 4; ++i)
#pragma unroll
    for (int j = 0; j < 4; ++j) acc[i][j] = zz;

  constexpr int ITERS = K / 32;
  for (int it = 0; it < ITERS; ++it) {
    *(u32x4*)&sA[so0] = ra0; *(u32x4*)&sA[so1] = ra1;
    *(u32x4*)&sB[so0] = rb0; *(u32x4*)&sB[so1] = rb1;
    __syncthreads();
    if (it + 1 < ITERS) {
      const int ko = (it + 1) * 32;
      ra0 = *(const u32x4*)(gA0 + ko);
      ra1 = *(const u32x4*)(gA0 + (size_t)64 * K + ko);
      rb0 = *(const u32x4*)(gB0 + ko);
      rb1 = *(const u32x4*)(gB0 + (size_t)64 * K + ko);
    }
    bf16x8 af[4], bfr[4];
#pragma unroll
    for (int mi = 0; mi < 4; ++mi) {
      int ar = wr * 64 + mi * 16 + c;
      af[mi] = *(const bf16x8*)&sA[ar * 32 + ((g * 8) ^ (((ar >> 1) & 3) * 8))];
    }
#pragma unroll
    for (int nj = 0; nj < 4; ++nj) {
      int br = wc * 64 + nj * 16 + c;
      bfr[nj] = *(const bf16x8*)&sB[br * 32 + ((g * 8) ^ (((br >> 1) & 3) * 8))];
    }
#pragma unroll
    for (int mi = 0; mi < 4; ++mi)
#pragma unroll
      for (int nj = 0; nj < 4; ++nj)
        acc[mi][nj] = __builtin_amdgcn_mfma_f32_16x16x32_bf16(af[mi], bfr[nj], acc[mi][nj], 0, 0, 0);
    __syncthreads();
  }

  const int row0 = bm * 128 + wr * 64;
  const int col0 = bn * 128 + wc * 64;
#pragma unroll
  for (int mi = 0; mi < 4; ++mi) {
#pragma unroll
    for (int nj = 0; nj < 4; ++nj) {
      const int rowb = row0 + mi * 16 + 4 * g;   // + r
      const int cc = col0 + nj * 16 + c;
      if constexpr (EPI == 0) {
        const int which = cc >> 9;
        const int hh = (cc >> 6) & 7;
        const int d = cc & 63;
        const int bi = rowb >> 11;
        const int s = rowb & (S_ - 1);
        if (which == 2) {  // V -> transposed [bh][d][s], 4 consecutive s packed
          u32x2 pk;
          pk.x = (u32)f2bf(acc[mi][nj][0]) | ((u32)f2bf(acc[mi][nj][1]) << 16);
          pk.y = (u32)f2bf(acc[mi][nj][2]) | ((u32)f2bf(acc[mi][nj][3]) << 16);
          *(u32x2*)(ea.vt + (((size_t)(bi * H_ + hh) * D_ + d) * S_ + s)) = pk;
        } else {           // Q/K with interleaved RoPE (partner channel via shfl_xor 1)
          u16* dst = (which == 0 ? ea.q : ea.k) + (((size_t)(bi * H_ + hh) * S_ + s) * D_ + d);
#pragma unroll
          for (int r = 0; r < 4; ++r) {
            float v = acc[mi][nj][r];
            float pv = __shfl_xor(v, 1, 64);
            int si = s + r;
            float cs = ea.cosT[si * 64 + d];
            float sn = ea.sinT[si * 64 + d];
            float o = v * cs + ((d & 1) ? pv : -pv) * sn;
            dst[(size_t)r * D_] = f2bf(o);
          }
        }
      } else if constexpr (EPI == 1) {
#pragma unroll
        for (int r = 0; r < 4; ++r) {
          size_t idx = (size_t)(rowb + r) * N + cc;
          ea.outf[idx] = acc[mi][nj][r] + ea.resid[idx];
        }
      } else if constexpr (EPI == 2) {
#pragma unroll
        for (int r = 0; r < 4; ++r)
          ea.outb[(size_t)(rowb + r) * N + cc] = f2bf(acc[mi][nj][r]);
      } else {  // EPI 3: silu(gate)*acc, in-place capable
#pragma unroll
        for (int r = 0; r < 4; ++r) {
          size_t idx = (size_t)(rowb + r) * N + cc;
          float gv = bf2f(ea.gate[idx]);
          float sil = gv / (1.f + __expf(-gv));
          ea.outb[idx] = f2bf(sil * acc[mi][nj][r]);
        }
      }
    }
  }
}

// ---------------- sliding-window flash attention ----------------
// grid (B*H, S/64); 4 waves, each wave owns 16 queries. Swapped QK^T:
// S^T = mfma(K,Q) so each lane owns one query column; online softmax per lane.
__global__ __launch_bounds__(256) void attn_k(const u16* __restrict__ Qb,
                                              const u16* __restrict__ Kb,
                                              const u16* __restrict__ Vt,
                                              u16* __restrict__ ao,
                                              const int* __restrict__ wsp) {
  const int bh = blockIdx.x;
  const int b = bh >> 3, h = bh & 7;
  const int qt = blockIdx.y;
  const int tid = threadIdx.x;
  const int w = tid >> 6, lane = tid & 63;
  const int g = lane >> 4, c = lane & 15;
  const int ws = *wsp;
  const int qw = qt * 64 + w * 16;
  const u16* Qh = Qb + (size_t)bh * S_ * D_;
  const u16* Kh = Kb + (size_t)bh * S_ * D_;
  const u16* Vh = Vt + (size_t)bh * D_ * S_;

  bf16x8 qf0 = *(const bf16x8*)(Qh + (qw + c) * D_ + g * 8);
  bf16x8 qf1 = *(const bf16x8*)(Qh + (qw + c) * D_ + 32 + g * 8);

  float mcur = -3e38f, lsum = 0.f;
  f32x4 O[4];
  f32x4 zz = {0.f, 0.f, 0.f, 0.f};
#pragma unroll
  for (int i = 0; i < 4; ++i) O[i] = zz;

  int lo = qw - ws + 1;
  if (lo < 0) lo = 0;
  for (int kb = lo & ~31; kb <= qw + 15; kb += 32) {
    f32x4 s0 = zz, s1 = zz;
    bf16x8 kf;
    kf = *(const bf16x8*)(Kh + (kb + c) * D_ + g * 8);
    s0 = __builtin_amdgcn_mfma_f32_16x16x32_bf16(kf, qf0, s0, 0, 0, 0);
    kf = *(const bf16x8*)(Kh + (kb + c) * D_ + 32 + g * 8);
    s0 = __builtin_amdgcn_mfma_f32_16x16x32_bf16(kf, qf1, s0, 0, 0, 0);
    kf = *(const bf16x8*)(Kh + (kb + 16 + c) * D_ + g * 8);
    s1 = __builtin_amdgcn_mfma_f32_16x16x32_bf16(kf, qf0, s1, 0, 0, 0);
    kf = *(const bf16x8*)(Kh + (kb + 16 + c) * D_ + 32 + g * 8);
    s1 = __builtin_amdgcn_mfma_f32_16x16x32_bf16(kf, qf1, s1, 0, 0, 0);

    const int q = qw + c;
    float p0[4], p1[4];
    float mloc = -3e38f;
#pragma unroll
    for (int r = 0; r < 4; ++r) {
      int k0i = kb + 4 * g + r;
      int k1i = k0i + 16;
      float va = s0[r] * 0.125f, vb = s1[r] * 0.125f;
      p0[r] = (q >= k0i && (q - k0i) < ws) ? va : -__builtin_inff();
      p1[r] = (q >= k1i && (q - k1i) < ws) ? vb : -__builtin_inff();
      mloc = fmaxf(mloc, fmaxf(p0[r], p1[r]));
    }
    mloc = fmaxf(mloc, __shfl_xor(mloc, 16, 64));
    mloc = fmaxf(mloc, __shfl_xor(mloc, 32, 64));
    float mnew = fmaxf(mcur, mloc);
    float alpha = __expf(mcur - mnew);
    float psum = 0.f;
#pragma unroll
    for (int r = 0; r < 4; ++r) {
      p0[r] = __expf(p0[r] - mnew);   // masked (-inf) -> 0
      p1[r] = __expf(p1[r] - mnew);
      psum += p0[r] + p1[r];
    }
    psum += __shfl_xor(psum, 16, 64);
    psum += __shfl_xor(psum, 32, 64);
    lsum = lsum * alpha + psum;
#pragma unroll
    for (int i = 0; i < 4; ++i) O[i] *= alpha;

    // redistribute P^T (C-layout: 4 keys/lane) into B-frag layout (8 keys/lane)
    union { bf16x8 v; u16 u[8]; } pf;
#pragma unroll
    for (int j = 0; j < 8; ++j) {
      int srcl = ((g & 1) * 2 + (j >> 2)) * 16 + c;
      float va = __shfl(p0[j & 3], srcl, 64);
      float vb = __shfl(p1[j & 3], srcl, 64);
      pf.u[j] = f2bf((g >= 2) ? vb : va);
    }
#pragma unroll
    for (int dt = 0; dt < 4; ++dt) {
      bf16x8 vf = *(const bf16x8*)(Vh + (size_t)(dt * 16 + c) * S_ + kb + g * 8);
      O[dt] = __builtin_amdgcn_mfma_f32_16x16x32_bf16(vf, pf.v, O[dt], 0, 0, 0);
    }
    mcur = mnew;
  }

  float inv = 1.f / lsum;
  __shared__ u16 ob[4][16][64];
#pragma unroll
  for (int dt = 0; dt < 4; ++dt)
#pragma unroll
    for (int r = 0; r < 4; ++r)
      ob[w][c][dt * 16 + 4 * g + r] = f2bf(O[dt][r] * inv);
  __syncthreads();
#pragma unroll
  for (int it = 0; it < 2; ++it) {
    int linear = tid + it * 256;
    int qrow = linear >> 3, ch = linear & 7;
    u32x4 v = *(const u32x4*)&ob[qrow >> 4][qrow & 15][ch * 8];
    *(u32x4*)(ao + ((size_t)(b * S_ + qt * 64 + qrow)) * E_ + h * D_ + ch * 8) = v;
  }
}

// ---------------- launcher ----------------
extern "C" void kernel_launch(void* const* d_in, const int* in_sizes, int n_in,
                              void* d_out, int out_size, void* d_ws, size_t ws_size,
                              hipStream_t stream) {
  const float* x      = (const float*)d_in[0];
  const float* rms1_w = (const float*)d_in[1];
  const float* rms2_w = (const float*)d_in[2];
  const float* qkv_w  = (const float*)d_in[3];
  const float* out_w  = (const float*)d_in[4];
  const float* cs_w1  = (const float*)d_in[5];
  const float* cs_w2  = (const float*)d_in[6];
  const float* gate_w = (const float*)d_in[7];
  const float* up_w   = (const float*)d_in[8];
  const float* down_w = (const float*)d_in[9];

  char* ws = (char*)d_ws;
  // offsets (bytes)
  constexpr size_t o_wqkv = 0;                       // 1536*512*2
  constexpr size_t o_wout = 1572864;                 // 512*512*2
  constexpr size_t o_wgate = 2097152;                // 2304*512*2
  constexpr size_t o_wup = 4456448;
  constexpr size_t o_wdown = 6815744;                // 512*2304*2
  constexpr size_t o_h = 9175040;                    // 8192*512*2  (aliased by attnout later)
  constexpr size_t o_stats = 17563648;               // 16KB
  constexpr size_t o_cos = 17580032;                 // 2048*64*4
  constexpr size_t o_sin = 18104320;
  constexpr size_t o_Q = 18628608;                   // 8192*512*2  (aliased by h2 later)
  constexpr size_t o_K = 27017216;
  constexpr size_t o_Vt = 35405824;
  constexpr size_t o_x2 = 43794432;                  // 8192*512*4
  constexpr size_t o_gate = 60571648;                // 8192*2304*2 (act in-place)
  // total ~98.3 MB

  u16* wqkv = (u16*)(ws + o_wqkv);
  u16* wout = (u16*)(ws + o_wout);
  u16* wgate = (u16*)(ws + o_wgate);
  u16* wup = (u16*)(ws + o_wup);
  u16* wdown = (u16*)(ws + o_wdown);
  u16* h = (u16*)(ws + o_h);
  float* stats = (float*)(ws + o_stats);
  float* cosT = (float*)(ws + o_cos);
  float* sinT = (float*)(ws + o_sin);
  u16* Qb = (u16*)(ws + o_Q);
  u16* Kb = (u16*)(ws + o_K);
  u16* Vt = (u16*)(ws + o_Vt);
  float* x2 = (float*)(ws + o_x2);
  u16* gateb = (u16*)(ws + o_gate);
  u16* attno = h;     // alias: h dead after G1/colsum
  u16* h2 = Qb;       // alias: Q dead after attention

  hipMemsetAsync(stats, 0, 16384, stream);
  cvt_k<<<768, 256, 0, stream>>>(qkv_w, wqkv, 1536 * 512);
  cvt_k<<<256, 256, 0, stream>>>(out_w, wout, 512 * 512);
  cvt_k<<<1152, 256, 0, stream>>>(gate_w, wgate, 2304 * 512);
  cvt_k<<<1152, 256, 0, stream>>>(up_w, wup, 2304 * 512);
  cvt_k<<<1152, 256, 0, stream>>>(down_w, wdown, 512 * 2304);
  ropetab_k<<<512, 256, 0, stream>>>(cosT, sinT);

  rmsnorm_k<<<8192, 256, 0, stream>>>(x, rms1_w, h);
  colsum_k<<<32, 256, 0, stream>>>(h, stats);
  wscalc_k<<<1, 128, 0, stream>>>(stats, cs_w1, cs_w2);

  EpiArgs ea{};
  ea.q = Qb; ea.k = Kb; ea.vt = Vt; ea.cosT = cosT; ea.sinT = sinT;
  gemm_k<1536, 512, 0><<<dim3(64, 12), 256, 0, stream>>>(h, wqkv, ea);

  attn_k<<<dim3(32, 32), 256, 0, stream>>>(Qb, Kb, Vt, attno, (const int*)(stats + 2056));

  EpiArgs e2{};
  e2.resid = x; e2.outf = x2;
  gemm_k<512, 512, 1><<<dim3(64, 4), 256, 0, stream>>>(attno, wout, e2);

  rmsnorm_k<<<8192, 256, 0, stream>>>(x2, rms2_w, h2);

  EpiArgs e3{};
  e3.outb = gateb;
  gemm_k<2304, 512, 2><<<dim3(64, 18), 256, 0, stream>>>(h2, wgate, e3);

  EpiArgs e4{};
  e4.gate = gateb; e4.outb = gateb;   // in-place: act = silu(gate)*up
  gemm_k<2304, 512, 3><<<dim3(64, 18), 256, 0, stream>>>(h2, wup, e4);

  EpiArgs e5{};
  e5.resid = x2; e5.outf = (float*)d_out;
  gemm_k<512, 2304, 1><<<dim3(64, 4), 256, 0, stream>>>(gateb, wdown, e5);

  (void)in_sizes; (void)n_in; (void)out_size; (void)ws_size;
}

// Round 5
// 402.824 us; speedup vs baseline: 1.1053x; 1.1053x over previous
//
#include <hip/hip_runtime.h>

typedef unsigned short u16;
typedef unsigned int   u32;
typedef __attribute__((ext_vector_type(4))) float  f32x4;
typedef __attribute__((ext_vector_type(8))) __bf16 bf16x8;
typedef __attribute__((ext_vector_type(4))) u32    u32x4;
typedef __attribute__((ext_vector_type(2))) u32    u32x2;

#define B_ 4
#define S_ 2048
#define E_ 512
#define H_ 8
#define D_ 64

__device__ __forceinline__ u16 f2bf(float f) {
  union { float f; u32 u; } a; a.f = f;
  u32 r = a.u + 0x7FFFu + ((a.u >> 16) & 1u);   // RNE
  return (u16)(r >> 16);
}
__device__ __forceinline__ float bf2f(u16 u) {
  union { u32 u; float f; } a; a.u = (u32)u << 16;
  return a.f;
}
__device__ __forceinline__ u32 pkbf(float lo, float hi) {  // bf16(lo) | bf16(hi)<<16
  u32 r;
  asm("v_cvt_pk_bf16_f32 %0, %1, %2" : "=v"(r) : "v"(lo), "v"(hi));
  return r;
}

// async global->LDS, 16B per lane; lds ptr must be wave-uniform (HW adds lane*16)
#define GLOAD16(gp, lp) __builtin_amdgcn_global_load_lds( \
    (const __attribute__((address_space(1))) void*)(gp),  \
    (__attribute__((address_space(3))) void*)(lp), 16, 0, 0)

// ---------------- weight fp32 -> bf16 convert ----------------
__global__ __launch_bounds__(256) void cvt_k(const float* __restrict__ s,
                                             u16* __restrict__ d, int n) {
  int i = (blockIdx.x * 256 + threadIdx.x) * 4;
  if (i >= n) return;
  f32x4 v = *(const f32x4*)(s + i);
  u32x2 o;
  o.x = pkbf(v[0], v[1]);
  o.y = pkbf(v[2], v[3]);
  *(u32x2*)(d + i) = o;
}

// ---------------- RoPE cos/sin table ----------------
__global__ __launch_bounds__(256) void ropetab_k(float* __restrict__ ct,
                                                 float* __restrict__ st) {
  int idx = blockIdx.x * 256 + threadIdx.x;   // S_*64 total
  int s = idx >> 6, j = idx & 63;
  float f = powf(10000.f, -(float)(j & 31) * (1.f / 32.f));
  float ang = (float)s * f;
  ct[idx] = cosf(ang);
  st[idx] = sinf(ang);
}

// ---------------- RMSNorm (row of 512), fp32 in -> bf16 out ----------------
__global__ __launch_bounds__(256) void rmsnorm_k(const float* __restrict__ x,
                                                 const float* __restrict__ wv,
                                                 u16* __restrict__ o) {
  const int row = blockIdx.x;
  const int t = threadIdx.x;
  const float* xr = x + (size_t)row * E_;
  float v0 = xr[t], v1 = xr[t + 256];
  float ss = v0 * v0 + v1 * v1;
#pragma unroll
  for (int m = 1; m < 64; m <<= 1) ss += __shfl_xor(ss, m, 64);
  __shared__ float red[4];
  if ((t & 63) == 0) red[t >> 6] = ss;
  __syncthreads();
  float tot = red[0] + red[1] + red[2] + red[3];
  float rms = 1.f / sqrtf(tot * (1.f / (float)E_) + 1e-6f);
  o[(size_t)row * E_ + t]       = f2bf(v0 * rms * wv[t]);
  o[(size_t)row * E_ + t + 256] = f2bf(v1 * rms * wv[t + 256]);
}

// ------------- column sums (xm) + batch sum/sumsq of h -------------
__global__ __launch_bounds__(256) void colsum_k(const u16* __restrict__ h,
                                                float* __restrict__ st) {
  const int b = blockIdx.x >> 3, ck = blockIdx.x & 7;
  const u16* hb = h + ((size_t)b * S_ + ck * 256) * E_;
  const int t = threadIdx.x;
  float a0 = 0, a1 = 0, s = 0, sq = 0;
  for (int r = 0; r < 256; ++r) {
    float v0 = bf2f(hb[(size_t)r * E_ + t]);
    float v1 = bf2f(hb[(size_t)r * E_ + t + 256]);
    a0 += v0; a1 += v1;
    s += v0 + v1; sq += v0 * v0 + v1 * v1;
  }
  atomicAdd(&st[8 + b * E_ + t], a0);
  atomicAdd(&st[8 + b * E_ + t + 256], a1);
#pragma unroll
  for (int m = 1; m < 64; m <<= 1) { s += __shfl_xor(s, m, 64); sq += __shfl_xor(sq, m, 64); }
  if ((t & 63) == 0) { atomicAdd(&st[b], s); atomicAdd(&st[4 + b], sq); }
}

// ------------- complexity -> window size scalar -------------
__global__ __launch_bounds__(128) void wscalc_k(float* __restrict__ st,
                                                const float* __restrict__ w1,
                                                const float* __restrict__ w2) {
  const int j = threadIdx.x;
  __shared__ float comp[4];
  __shared__ float tw[2];
  float dot[4] = {0.f, 0.f, 0.f, 0.f};
  const float* w1r = w1 + (size_t)j * E_;
  for (int e = 0; e < E_; ++e) {
    float wv = w1r[e];
    dot[0] += st[8 + 0 * E_ + e] * wv;
    dot[1] += st[8 + 1 * E_ + e] * wv;
    dot[2] += st[8 + 2 * E_ + e] * wv;
    dot[3] += st[8 + 3 * E_ + e] * wv;
  }
  for (int b = 0; b < 4; ++b) {
    float d = dot[b] * (1.f / (float)S_);
    float si = d / (1.f + __expf(-d));
    float term = si * w2[j];
#pragma unroll
    for (int m = 1; m < 64; m <<= 1) term += __shfl_xor(term, m, 64);
    __syncthreads();
    if ((j & 63) == 0) tw[j >> 6] = term;
    __syncthreads();
    if (j == 0) {
      float pre = tw[0] + tw[1];
      float learned = 1.f / (1.f + __expf(-pre));
      const float n = (float)S_ * (float)E_;
      float sum = st[b], ssq = st[4 + b];
      float var = (ssq - sum * sum / n) / (n - 1.f);
      float vn = 1.f / (1.f + __expf(-(var * 10.f - 5.f)));
      comp[b] = 0.5f * (vn + learned);
    }
    __syncthreads();
  }
  if (j == 0) {
    float mean = 0.25f * (comp[0] + comp[1] + comp[2] + comp[3]);
    float wsf = 256.f + mean * 768.f;
    int v = (int)wsf;
    v = v < 256 ? 256 : (v > S_ ? S_ : v);
    ((int*)st)[2056] = v;
  }
}

// ---------------- 128x128 bf16 MFMA GEMM (m97-style gload_lds staging) ----------------
// C = A[M][K] * W[N][K]^T.  EPI: 0 = QKV (RoPE + scatter), 1 = +resid -> f32 out
struct EpiArgs {
  u16* q; u16* k; u16* vt;
  const float* cosT; const float* sinT;
  const float* resid; float* outf;
};

template <int N, int K, int EPI, int WAVES>
__global__ __launch_bounds__(WAVES * 64) void gemm_k(const u16* __restrict__ A,
                                                     const u16* __restrict__ W,
                                                     EpiArgs ea) {
  __shared__ u16 sA[128 * 32];
  __shared__ u16 sB[128 * 32];
  const int tid = threadIdx.x;
  const int bm = blockIdx.x, bn = blockIdx.y;
  const int lane = tid & 63, w = tid >> 6;
  const int g = lane >> 4, c = lane & 15;
  constexpr int MI = (WAVES == 4) ? 4 : 2;
  const int wrow = (w >> 1) * ((WAVES == 4) ? 64 : 32);
  const int wcol = (w & 1) * 64;

  const int srow = tid >> 2, sch = tid & 3;
  const u16* gA = A + (size_t)(bm * 128 + srow) * K + sch * 8;
  const u16* gB = W + (size_t)(bn * 128 + srow) * K + sch * 8;
  char* lA0 = (char*)sA + w * 1024;
  char* lB0 = (char*)sB + w * 1024;

  f32x4 acc[MI][4];
  f32x4 zz = {0.f, 0.f, 0.f, 0.f};
#pragma unroll
  for (int i = 0; i < MI; ++i)
#pragma unroll
    for (int j = 0; j < 4; ++j) acc[i][j] = zz;

  for (int it = 0; it < K / 32; ++it) {
    const int ko = it * 32;
    GLOAD16(gA + ko, lA0);
    GLOAD16(gB + ko, lB0);
    if constexpr (WAVES == 4) {
      GLOAD16(gA + (size_t)64 * K + ko, lA0 + 4096);
      GLOAD16(gB + (size_t)64 * K + ko, lB0 + 4096);
    }
    __syncthreads();
    bf16x8 af[MI], bfr[4];
#pragma unroll
    for (int mi = 0; mi < MI; ++mi)
      af[mi] = *(const bf16x8*)&sA[(wrow + mi * 16 + c) * 32 + g * 8];
#pragma unroll
    for (int nj = 0; nj < 4; ++nj)
      bfr[nj] = *(const bf16x8*)&sB[(wcol + nj * 16 + c) * 32 + g * 8];
#pragma unroll
    for (int mi = 0; mi < MI; ++mi)
#pragma unroll
      for (int nj = 0; nj < 4; ++nj)
        acc[mi][nj] = __builtin_amdgcn_mfma_f32_16x16x32_bf16(af[mi], bfr[nj], acc[mi][nj], 0, 0, 0);
    __syncthreads();
  }

#pragma unroll
  for (int mi = 0; mi < MI; ++mi) {
#pragma unroll
    for (int nj = 0; nj < 4; ++nj) {
      const int rowb = bm * 128 + wrow + mi * 16 + 4 * g;
      const int cc = bn * 128 + wcol + nj * 16 + c;
      if constexpr (EPI == 0) {
        const int which = cc >> 9;
        const int hh = (cc >> 6) & 7;
        const int d = cc & 63;
        const int bi = rowb >> 11;
        const int s = rowb & (S_ - 1);
        if (which == 2) {  // V -> transposed [bh][d][s]
          u32x2 pk;
          pk.x = pkbf(acc[mi][nj][0], acc[mi][nj][1]);
          pk.y = pkbf(acc[mi][nj][2], acc[mi][nj][3]);
          *(u32x2*)(ea.vt + (((size_t)(bi * H_ + hh) * D_ + d) * S_ + s)) = pk;
        } else {           // Q/K with interleaved RoPE
          u16* dst = (which == 0 ? ea.q : ea.k) + (((size_t)(bi * H_ + hh) * S_ + s) * D_ + d);
#pragma unroll
          for (int r = 0; r < 4; ++r) {
            float v = acc[mi][nj][r];
            float pv = __shfl_xor(v, 1, 64);
            int si = s + r;
            float cs = ea.cosT[si * 64 + d];
            float sn = ea.sinT[si * 64 + d];
            float o = v * cs + ((d & 1) ? pv : -pv) * sn;
            dst[(size_t)r * D_] = f2bf(o);
          }
        }
      } else {  // EPI 1: +resid -> f32
#pragma unroll
        for (int r = 0; r < 4; ++r) {
          size_t idx = (size_t)(rowb + r) * N + cc;
          ea.outf[idx] = acc[mi][nj][r] + ea.resid[idx];
        }
      }
    }
  }
}

// ---------------- fused gate+up GEMM with silu epilogue (8 waves) ----------------
__global__ __launch_bounds__(512) void gemmgu_k(const u16* __restrict__ A,
                                                const u16* __restrict__ Wg,
                                                const u16* __restrict__ Wu,
                                                u16* __restrict__ outb) {
  __shared__ u16 sA[128 * 32];
  __shared__ u16 sG[128 * 32];
  __shared__ u16 sU[128 * 32];
  const int tid = threadIdx.x;
  const int bm = blockIdx.x, bn = blockIdx.y;
  const int lane = tid & 63, w = tid >> 6;
  const int g = lane >> 4, c = lane & 15;
  const int wrow = (w >> 1) * 32;
  const int wcol = (w & 1) * 64;

  const int srow = tid >> 2, sch = tid & 3;
  const u16* gA = A + (size_t)(bm * 128 + srow) * 512 + sch * 8;
  const u16* gG = Wg + (size_t)(bn * 128 + srow) * 512 + sch * 8;
  const u16* gU = Wu + (size_t)(bn * 128 + srow) * 512 + sch * 8;
  char* lA0 = (char*)sA + w * 1024;
  char* lG0 = (char*)sG + w * 1024;
  char* lU0 = (char*)sU + w * 1024;

  f32x4 accg[2][4], accu[2][4];
  f32x4 zz = {0.f, 0.f, 0.f, 0.f};
#pragma unroll
  for (int i = 0; i < 2; ++i)
#pragma unroll
    for (int j = 0; j < 4; ++j) { accg[i][j] = zz; accu[i][j] = zz; }

  for (int it = 0; it < 16; ++it) {
    const int ko = it * 32;
    GLOAD16(gA + ko, lA0);
    GLOAD16(gG + ko, lG0);
    GLOAD16(gU + ko, lU0);
    __syncthreads();
    bf16x8 af[2], bg[4], bu[4];
#pragma unroll
    for (int mi = 0; mi < 2; ++mi)
      af[mi] = *(const bf16x8*)&sA[(wrow + mi * 16 + c) * 32 + g * 8];
#pragma unroll
    for (int nj = 0; nj < 4; ++nj) {
      bg[nj] = *(const bf16x8*)&sG[(wcol + nj * 16 + c) * 32 + g * 8];
      bu[nj] = *(const bf16x8*)&sU[(wcol + nj * 16 + c) * 32 + g * 8];
    }
#pragma unroll
    for (int mi = 0; mi < 2; ++mi)
#pragma unroll
      for (int nj = 0; nj < 4; ++nj) {
        accg[mi][nj] = __builtin_amdgcn_mfma_f32_16x16x32_bf16(af[mi], bg[nj], accg[mi][nj], 0, 0, 0);
        accu[mi][nj] = __builtin_amdgcn_mfma_f32_16x16x32_bf16(af[mi], bu[nj], accu[mi][nj], 0, 0, 0);
      }
    __syncthreads();
  }

#pragma unroll
  for (int mi = 0; mi < 2; ++mi) {
#pragma unroll
    for (int nj = 0; nj < 4; ++nj) {
      const int rowb = bm * 128 + wrow + mi * 16 + 4 * g;
      const int cc = bn * 128 + wcol + nj * 16 + c;
#pragma unroll
      for (int r = 0; r < 4; ++r) {
        float gv = accg[mi][nj][r];
        float uv = accu[mi][nj][r];
        float sil = gv / (1.f + __expf(-gv));
        outb[(size_t)(rowb + r) * 2304 + cc] = f2bf(sil * uv);
      }
    }
  }
}

// ---------------- sliding-window flash attention, KBLK=64 ----------------
__global__ __launch_bounds__(256) void attn_k(const u16* __restrict__ Qb,
                                              const u16* __restrict__ Kb,
                                              const u16* __restrict__ Vt,
                                              u16* __restrict__ ao,
                                              const int* __restrict__ wsp) {
  const int bh = blockIdx.x;
  const int b = bh >> 3, h = bh & 7;
  const int qt = blockIdx.y;
  const int tid = threadIdx.x;
  const int w = tid >> 6, lane = tid & 63;
  const int g = lane >> 4, c = lane & 15;
  const int ws = *wsp;
  const int qw = qt * 64 + w * 16;
  const u16* Qh = Qb + (size_t)bh * S_ * D_;
  const u16* Kh = Kb + (size_t)bh * S_ * D_;
  const u16* Vh = Vt + (size_t)bh * D_ * S_;

  bf16x8 qf0 = *(const bf16x8*)(Qh + (qw + c) * D_ + g * 8);
  bf16x8 qf1 = *(const bf16x8*)(Qh + (qw + c) * D_ + 32 + g * 8);

  const float SCL = 0.125f * 1.44269504089f;   // d^-0.5 * log2(e)
  float m2 = -3e38f, lsum = 0.f;
  f32x4 O[4];
  f32x4 zz = {0.f, 0.f, 0.f, 0.f};
#pragma unroll
  for (int i = 0; i < 4; ++i) O[i] = zz;

  int lo = qw - ws + 1;
  if (lo < 0) lo = 0;
  const int q = qw + c;
  for (int kb = lo & ~63; kb <= qw + 15; kb += 64) {
    // QK^T: 4 sub-tiles of 16 keys
    f32x4 st[4];
#pragma unroll
    for (int t = 0; t < 4; ++t) {
      const u16* kp = Kh + (kb + 16 * t + c) * D_;
      f32x4 s = zz;
      s = __builtin_amdgcn_mfma_f32_16x16x32_bf16(*(const bf16x8*)(kp + g * 8), qf0, s, 0, 0, 0);
      s = __builtin_amdgcn_mfma_f32_16x16x32_bf16(*(const bf16x8*)(kp + 32 + g * 8), qf1, s, 0, 0, 0);
      st[t] = s;
    }
    // mask + block max (log2 domain)
    float p[4][4];
    float bm = -3e38f;
#pragma unroll
    for (int t = 0; t < 4; ++t)
#pragma unroll
      for (int r = 0; r < 4; ++r) {
        int ki = kb + 16 * t + 4 * g + r;
        float v = st[t][r] * SCL;
        bool ok = (q >= ki) && (q - ki) < ws;
        p[t][r] = ok ? v : -__builtin_inff();
        bm = fmaxf(bm, p[t][r]);
      }
    bm = fmaxf(bm, __shfl_xor(bm, 16, 64));
    bm = fmaxf(bm, __shfl_xor(bm, 32, 64));
    if (!__all(bm - m2 <= 8.f)) {          // T13 defer-max
      float mnew = fmaxf(m2, bm);
      float al = exp2f(m2 - mnew);
      lsum *= al;
#pragma unroll
      for (int i = 0; i < 4; ++i) O[i] *= al;
      m2 = mnew;
    }
    float psum = 0.f;
#pragma unroll
    for (int t = 0; t < 4; ++t)
#pragma unroll
      for (int r = 0; r < 4; ++r) {
        p[t][r] = exp2f(p[t][r] - m2);     // masked -> 0
        psum += p[t][r];
      }
    psum += __shfl_xor(psum, 16, 64);
    psum += __shfl_xor(psum, 32, 64);
    lsum += psum;

    // pack P to bf16 pairs, redistribute to PV B-frag layout
    u32 pp[4][2];
#pragma unroll
    for (int t = 0; t < 4; ++t) {
      pp[t][0] = pkbf(p[t][0], p[t][1]);
      pp[t][1] = pkbf(p[t][2], p[t][3]);
    }
    const int lA = (g & 1) * 32 + c;   // source lane for j<4
    const int lB = lA + 16;            // source lane for j>=4
    const int hi = g >> 1;
    union { bf16x8 v; u32 u[4]; } pf0, pf1;
#pragma unroll
    for (int wi = 0; wi < 2; ++wi) {
      u32 a0 = (u32)__shfl((int)pp[0][wi], lA, 64);
      u32 a1 = (u32)__shfl((int)pp[1][wi], lA, 64);
      u32 a2 = (u32)__shfl((int)pp[2][wi], lA, 64);
      u32 a3 = (u32)__shfl((int)pp[3][wi], lA, 64);
      u32 b0 = (u32)__shfl((int)pp[0][wi], lB, 64);
      u32 b1 = (u32)__shfl((int)pp[1][wi], lB, 64);
      u32 b2 = (u32)__shfl((int)pp[2][wi], lB, 64);
      u32 b3 = (u32)__shfl((int)pp[3][wi], lB, 64);
      pf0.u[wi]     = hi ? a1 : a0;
      pf0.u[2 + wi] = hi ? b1 : b0;
      pf1.u[wi]     = hi ? a3 : a2;
      pf1.u[2 + wi] = hi ? b3 : b2;
    }
    // PV: O^T[d][q] += V^T[d][k] P[k][q]
#pragma unroll
    for (int dt = 0; dt < 4; ++dt) {
      const u16* vp = Vh + (size_t)(dt * 16 + c) * S_ + kb;
      O[dt] = __builtin_amdgcn_mfma_f32_16x16x32_bf16(*(const bf16x8*)(vp + g * 8), pf0.v, O[dt], 0, 0, 0);
      O[dt] = __builtin_amdgcn_mfma_f32_16x16x32_bf16(*(const bf16x8*)(vp + 32 + g * 8), pf1.v, O[dt], 0, 0, 0);
    }
  }

  float inv = 1.f / lsum;
  __shared__ u16 ob[4][16][80];   // padded rows: 160B -> no 16-way bank conflict
#pragma unroll
  for (int dt = 0; dt < 4; ++dt)
#pragma unroll
    for (int r = 0; r < 4; ++r)
      ob[w][c][dt * 16 + 4 * g + r] = f2bf(O[dt][r] * inv);
  __syncthreads();
#pragma unroll
  for (int it = 0; it < 2; ++it) {
    int linear = tid + it * 256;
    int qrow = linear >> 3, ch = linear & 7;
    u32x4 v = *(const u32x4*)&ob[qrow >> 4][qrow & 15][ch * 8];
    *(u32x4*)(ao + ((size_t)(b * S_ + qt * 64 + qrow)) * E_ + h * D_ + ch * 8) = v;
  }
}

// ---------------- launcher ----------------
extern "C" void kernel_launch(void* const* d_in, const int* in_sizes, int n_in,
                              void* d_out, int out_size, void* d_ws, size_t ws_size,
                              hipStream_t stream) {
  const float* x      = (const float*)d_in[0];
  const float* rms1_w = (const float*)d_in[1];
  const float* rms2_w = (const float*)d_in[2];
  const float* qkv_w  = (const float*)d_in[3];
  const float* out_w  = (const float*)d_in[4];
  const float* cs_w1  = (const float*)d_in[5];
  const float* cs_w2  = (const float*)d_in[6];
  const float* gate_w = (const float*)d_in[7];
  const float* up_w   = (const float*)d_in[8];
  const float* down_w = (const float*)d_in[9];

  char* ws = (char*)d_ws;
  constexpr size_t o_wqkv = 0;                       // 1536*512*2
  constexpr size_t o_wout = 1572864;                 // 512*512*2
  constexpr size_t o_wgate = 2097152;                // 2304*512*2
  constexpr size_t o_wup = 4456448;
  constexpr size_t o_wdown = 6815744;                // 512*2304*2
  constexpr size_t o_h = 9175040;                    // 8192*512*2  (alias: attnout)
  constexpr size_t o_stats = 17563648;               // 16KB
  constexpr size_t o_cos = 17580032;                 // 2048*64*4
  constexpr size_t o_sin = 18104320;
  constexpr size_t o_Q = 18628608;                   // 8192*512*2  (alias: h2)
  constexpr size_t o_K = 27017216;
  constexpr size_t o_Vt = 35405824;
  constexpr size_t o_x2 = 43794432;                  // 8192*512*4
  constexpr size_t o_gate = 60571648;                // 8192*2304*2

  u16* wqkv = (u16*)(ws + o_wqkv);
  u16* wout = (u16*)(ws + o_wout);
  u16* wgate = (u16*)(ws + o_wgate);
  u16* wup = (u16*)(ws + o_wup);
  u16* wdown = (u16*)(ws + o_wdown);
  u16* h = (u16*)(ws + o_h);
  float* stats = (float*)(ws + o_stats);
  float* cosT = (float*)(ws + o_cos);
  float* sinT = (float*)(ws + o_sin);
  u16* Qb = (u16*)(ws + o_Q);
  u16* Kb = (u16*)(ws + o_K);
  u16* Vt = (u16*)(ws + o_Vt);
  float* x2 = (float*)(ws + o_x2);
  u16* gateb = (u16*)(ws + o_gate);
  u16* attno = h;
  u16* h2 = Qb;

  hipMemsetAsync(stats, 0, 16384, stream);
  cvt_k<<<768, 256, 0, stream>>>(qkv_w, wqkv, 1536 * 512);
  cvt_k<<<256, 256, 0, stream>>>(out_w, wout, 512 * 512);
  cvt_k<<<1152, 256, 0, stream>>>(gate_w, wgate, 2304 * 512);
  cvt_k<<<1152, 256, 0, stream>>>(up_w, wup, 2304 * 512);
  cvt_k<<<1152, 256, 0, stream>>>(down_w, wdown, 512 * 2304);
  ropetab_k<<<512, 256, 0, stream>>>(cosT, sinT);

  rmsnorm_k<<<8192, 256, 0, stream>>>(x, rms1_w, h);
  colsum_k<<<32, 256, 0, stream>>>(h, stats);
  wscalc_k<<<1, 128, 0, stream>>>(stats, cs_w1, cs_w2);

  EpiArgs ea{};
  ea.q = Qb; ea.k = Kb; ea.vt = Vt; ea.cosT = cosT; ea.sinT = sinT;
  gemm_k<1536, 512, 0, 4><<<dim3(64, 12), 256, 0, stream>>>(h, wqkv, ea);

  attn_k<<<dim3(32, 32), 256, 0, stream>>>(Qb, Kb, Vt, attno, (const int*)(stats + 2056));

  EpiArgs e2{};
  e2.resid = x; e2.outf = x2;
  gemm_k<512, 512, 1, 8><<<dim3(64, 4), 512, 0, stream>>>(attno, wout, e2);

  rmsnorm_k<<<8192, 256, 0, stream>>>(x2, rms2_w, h2);

  gemmgu_k<<<dim3(64, 18), 512, 0, stream>>>(h2, wgate, wup, gateb);

  EpiArgs e5{};
  e5.resid = x2; e5.outf = (float*)d_out;
  gemm_k<512, 2304, 1, 8><<<dim3(64, 4), 512, 0, stream>>>(gateb, wdown, e5);

  (void)in_sizes; (void)n_in; (void)out_size; (void)ws_size;
}